// Round 11
// baseline (224.985 us; speedup 1.0000x reference)
//
#include <hip/hip_runtime.h>

// TopKRouter: logits = hs[32768,4096] @ gate_w[64,4096]^T ; top-2 + softmax.
// f32 GEMM via 3-limb truncation split (6 MFMA products, si+sj<=2); limb
// values and per-accumulator product order identical to verified R3..R10.
//
// R11: DRAM-page-friendly traversal. M=32 rows/block, BK=256 f32: each
// global_load_lds instruction reads ONE ROW'S 1 KB CONTIGUOUSLY (a full HBM
// page visit; successive supertiles continue the row at +1 KB). R9's probe
// showed this access class streams at 5.85 TB/s vs ~3.1 TB/s for the
// 256-B-strided pattern every earlier round used (page thrashing).
// LDS: 2 x 32 KB double buffer (65536 static). 1024 blocks x 512 thr,
// 2 blocks/CU = 16 waves/CU. Wave = 16 rows x 16 experts (acc = 1 f32x4).
// Swizzle per rule #21: pre-swizzled DMA source, linear dest, swizzled read.

#define NT    512
#define TT    32768
#define HD    4096
#define NE    64
#define MROWS 32
#define NSUP  16             // supertiles of BK=256 f32 (8 K-steps each)
#define BUFB  32768u

typedef __attribute__((ext_vector_type(8))) short bf16x8;
typedef __attribute__((ext_vector_type(4))) float f32x4;

#define MFMA __builtin_amdgcn_mfma_f32_16x16x32_bf16

__device__ __forceinline__ bf16x8 u2b(uint4 u) { return __builtin_bit_cast(bf16x8, u); }
__device__ __forceinline__ float4 b4f(uint4 u) { return __builtin_bit_cast(float4, u); }

__device__ __forceinline__ void gload_lds16(const void* g, void* l) {
  __builtin_amdgcn_global_load_lds(
      (const __attribute__((address_space(1))) void*)g,
      (__attribute__((address_space(3))) void*)l, 16, 0, 0);
}

// Exact 3-limb truncation split of 8 f32 -> 3 packed bf16x8 (as uint4).
__device__ __forceinline__ void tsplit8(float4 a, float4 b,
                                        uint4& o0, uint4& o1, uint4& o2) {
  float f[8] = {a.x, a.y, a.z, a.w, b.x, b.y, b.z, b.w};
  unsigned p0[4], p1[4], p2[4];
#pragma unroll
  for (int j = 0; j < 4; ++j) {
    float x0 = f[2 * j], x1 = f[2 * j + 1];
    unsigned u0 = __float_as_uint(x0) & 0xffff0000u;
    unsigned u1 = __float_as_uint(x1) & 0xffff0000u;
    float r0 = x0 - __uint_as_float(u0);
    float r1 = x1 - __uint_as_float(u1);
    unsigned v0 = __float_as_uint(r0) & 0xffff0000u;
    unsigned v1 = __float_as_uint(r1) & 0xffff0000u;
    float s0 = r0 - __uint_as_float(v0);
    float s1 = r1 - __uint_as_float(v1);
    p0[j] = (u0 >> 16) | u1;
    p1[j] = (v0 >> 16) | v1;
    p2[j] = (__float_as_uint(s0) >> 16) | (__float_as_uint(s1) & 0xffff0000u);
  }
  o0 = make_uint4(p0[0], p0[1], p0[2], p0[3]);
  o1 = make_uint4(p1[0], p1[1], p1[2], p1[3]);
  o2 = make_uint4(p2[0], p2[1], p2[2], p2[3]);
}

// ---- Pre-kernel: pack gate_w into fragment-major bf16 limb blocks ----
// uint4 index = ((g*3+L)*4+F)*64 + (lg*16 + (e&15)); g = K-step. (R7-verified)
__global__ __launch_bounds__(256)
void prepack_w_kernel(const float* __restrict__ W, uint4* __restrict__ Bp) {
  const int t  = blockIdx.x * 256 + threadIdx.x;
  const int e  = t >> 9;
  const int k0 = (t & 511) * 8;
  const float4* wp = (const float4*)(W + (size_t)e * HD + k0);
  uint4 o0, o1, o2;
  tsplit8(wp[0], wp[1], o0, o1, o2);
  const int ts = k0 >> 5;
  const int lg = (k0 >> 3) & 3;
  const int f  = e >> 4;
  const int ln = lg * 16 + (e & 15);
  Bp[(((ts * 3 + 0) * 4 + f) << 6) + ln] = o0;
  Bp[(((ts * 3 + 1) * 4 + f) << 6) + ln] = o1;
  Bp[(((ts * 3 + 2) * 4 + f) << 6) + ln] = o2;
}

// ---- Main kernel ----
__global__ __launch_bounds__(NT, 4)
void router_page_kernel(const float* __restrict__ A, const uint4* __restrict__ Bp,
                        float* __restrict__ outw, float* __restrict__ outi,
                        float* __restrict__ outl) {
  __shared__ __align__(16) unsigned char smem[65536];   // 2 x 32 KB

  const int tid  = threadIdx.x;
  const int bm   = blockIdx.x;      // 0..1023
  const int lane = tid & 63;
  const int w    = tid >> 6;        // wave 0..7
  const int wm   = w >> 2;          // 0..1 (row half)
  const int wn   = w & 3;           // 0..3 (expert quarter)
  const int l15  = lane & 15;
  const int lg   = lane >> 4;       // 0..3
  const unsigned key = (unsigned)(l15 & 7);   // read-side swizzle key

  const char* Ab = (const char*)A;

  // DMA: instr j covers row r = w*4+j ENTIRELY (64 lanes x 16 B = 1 KB
  // contiguous = one page visit). Source pre-swizzled: lane fills dest
  // granule `lane`, so it fetches logical granule lane ^ (r&7).
  unsigned soff[4], ldst[4];
#pragma unroll
  for (int j = 0; j < 4; ++j) {
    const int r = w * 4 + j;
    soff[j] = (unsigned)((bm * MROWS + r) * (HD * 4))
            + (((unsigned)lane ^ ((unsigned)r & 7u)) << 4);
    ldst[j] = (unsigned)(r * 1024);
  }

#define DMA(T, BOFF) { \
    _Pragma("unroll") \
    for (int j = 0; j < 4; ++j) \
      gload_lds16(Ab + (size_t)soff[j] + (size_t)(T) * 1024, \
                  smem + (BOFF) + ldst[j]); }

  // B limb table: per K-step g, limb L, frag F: uint4 idx = g*768 + L*256 + F*64 + lane.
  const uint4* pb = Bp + wn * 64 + lane;

  const unsigned abase = (unsigned)((wm * 16 + l15) * 1024);

  f32x4 acc = {0.f, 0.f, 0.f, 0.f};

  // One K-step: 3 B loads (L2), 2 swizzled ds_read_b128 (raw A), 1 tsplit8,
  // 6 MFMA in the verified per-accumulator product order.
#define STEP(BOFF, G, S) { \
    const uint4* q_ = pb + (size_t)(G) * 768; \
    const uint4 b0_ = q_[0], b1_ = q_[256], b2_ = q_[512]; \
    const unsigned g0_ = (unsigned)((S) * 8 + lg * 2); \
    const unsigned char* ab_ = smem + (BOFF) + abase; \
    const uint4 alo_ = *(const uint4*)(ab_ + ((g0_ ^ key) << 4)); \
    const uint4 ahi_ = *(const uint4*)(ab_ + (((g0_ + 1) ^ key) << 4)); \
    uint4 x0_, x1_, x2_; \
    tsplit8(b4f(alo_), b4f(ahi_), x0_, x1_, x2_); \
    const bf16x8 a0_ = u2b(x0_), a1_ = u2b(x1_), a2_ = u2b(x2_); \
    acc = MFMA(a0_, u2b(b2_), acc, 0, 0, 0); \
    acc = MFMA(a1_, u2b(b1_), acc, 0, 0, 0); \
    acc = MFMA(a2_, u2b(b0_), acc, 0, 0, 0); \
    acc = MFMA(a0_, u2b(b1_), acc, 0, 0, 0); \
    acc = MFMA(a1_, u2b(b0_), acc, 0, 0, 0); \
    acc = MFMA(a0_, u2b(b0_), acc, 0, 0, 0); }

  // Prologue: fill buffer 0 with supertile 0.
  DMA(0, 0u)

  unsigned cb = 0;
#pragma unroll 1
  for (int t = 0; t < NSUP; ++t) {
    // DMA(t) was issued one full supertile of compute ago -> near-free wait.
    asm volatile("s_waitcnt vmcnt(0)" ::: "memory");
    __builtin_amdgcn_s_barrier();
    __builtin_amdgcn_sched_barrier(0);
    if (t + 1 < NSUP) { DMA(t + 1, cb ^ BUFB) }
    __builtin_amdgcn_sched_barrier(0);
    const int g0 = t * 8;
    STEP(cb, g0 + 0, 0) STEP(cb, g0 + 1, 1)
    STEP(cb, g0 + 2, 2) STEP(cb, g0 + 3, 3)
    STEP(cb, g0 + 4, 4) STEP(cb, g0 + 5, 5)
    STEP(cb, g0 + 6, 6) STEP(cb, g0 + 7, 7)
    cb ^= BUFB;
  }

  // ---- Epilogue: logits to global + LDS, then top-2 + softmax ----
  // lf occupies buf0 (< 8.4 KB); final compute read buf1 only -> no overlap.
  const int t0 = bm * MROWS;
  float* lf = (float*)smem;            // [32][65] f32

  {
    const int e = wn * 16 + l15;
#pragma unroll
    for (int r = 0; r < 4; ++r) {
      const int row = wm * 16 + lg * 4 + r;
      const float v = acc[r];
      outl[(size_t)(t0 + row) * NE + e] = v;
      lf[row * 65 + e] = v;
    }
  }

  __syncthreads();

  if (tid < MROWS) {
    const int t = tid;
    float m1 = -1e30f, m2 = -1e30f;
    int i1 = 0, i2 = 0;
#pragma unroll
    for (int e = 0; e < NE; ++e) {
      float v = lf[t * 65 + e];
      if (v > m1)      { m2 = m1; i2 = i1; m1 = v; i1 = e; }
      else if (v > m2) { m2 = v; i2 = e; }
    }
    float e2  = expf(m2 - m1);
    float inv = 1.0f / (1.0f + e2);
    outw[(size_t)(t0 + t) * 2 + 0] = inv;
    outw[(size_t)(t0 + t) * 2 + 1] = e2 * inv;
    outi[(size_t)(t0 + t) * 2 + 0] = (float)i1;   // indices as floats
    outi[(size_t)(t0 + t) * 2 + 1] = (float)i2;
  }
}

// ---- Fallback (R3 LDS kernel, verified): used only if ws_size too small ----
#define PROD1(AM0, AM1, BS0, BS1) \
    acc00 = MFMA(AM0, BS0, acc00, 0, 0, 0); \
    acc01 = MFMA(AM0, BS1, acc01, 0, 0, 0); \
    acc10 = MFMA(AM1, BS0, acc10, 0, 0, 0); \
    acc11 = MFMA(AM1, BS1, acc11, 0, 0, 0);

__global__ __launch_bounds__(256, 2)
void topk_router_lds(const float* __restrict__ A, const float* __restrict__ W,
                     float* __restrict__ outw, float* __restrict__ outi,
                     float* __restrict__ outl) {
  __shared__ __align__(16) unsigned char smem[49152];
  const int tid  = threadIdx.x;
  const int bm   = blockIdx.x;
  const int lane = tid & 63;
  const int wid  = tid >> 6;
  const int wr   = wid >> 1;
  const int wc   = wid & 1;
  const int l15  = lane & 15;
  const int lg   = lane >> 4;
  const int s_r  = tid >> 2;
  const int s_cb = (tid & 3) << 3;
  const float* aball = A + (size_t)(bm * 64 + s_r) * HD + s_cb;
  const float* bball = W + (size_t)s_r * HD + s_cb;
  const unsigned wswz  = ((unsigned)((s_r >> 1) & 3)) << 4;
  const unsigned wbyte = (unsigned)(s_r * 64) + (((unsigned)(s_cb * 2)) ^ wswz);
  f32x4 acc00 = {0.f,0.f,0.f,0.f}, acc01 = {0.f,0.f,0.f,0.f};
  f32x4 acc10 = {0.f,0.f,0.f,0.f}, acc11 = {0.f,0.f,0.f,0.f};
  float4 aE0, aE1, bE0, bE1, aO0, aO1, bO0, bO1;
#define LOADS(T, A0, A1, B0, B1) { \
    const float4* ap = (const float4*)(aball + (size_t)(T) * 32); \
    A0 = ap[0]; A1 = ap[1]; \
    const float4* bp = (const float4*)(bball + (size_t)(T) * 32); \
    B0 = bp[0]; B1 = bp[1]; }
#define CONVW2(BB, A0, A1, B0, B1) { \
    uint4 o0, o1, o2; \
    tsplit8(A0, A1, o0, o1, o2); \
    *(uint4*)(smem + (BB) +     0 + wbyte) = o0; \
    *(uint4*)(smem + (BB) +  4096 + wbyte) = o1; \
    *(uint4*)(smem + (BB) +  8192 + wbyte) = o2; \
    tsplit8(B0, B1, o0, o1, o2); \
    *(uint4*)(smem + (BB) + 12288 + wbyte) = o0; \
    *(uint4*)(smem + (BB) + 16384 + wbyte) = o1; \
    *(uint4*)(smem + (BB) + 20480 + wbyte) = o2; }
  auto compute = [&](int bb) {
    bf16x8 a0m0, a0m1, a1m0, a1m1, a2m0, a2m1;
    bf16x8 b0n0, b0n1, b1n0, b1n1, b2n0, b2n1;
    const unsigned kb = (unsigned)(lg * 16);
#define LDA(SI, MI, DST) { \
    int row = wr * 32 + (MI) * 16 + l15; \
    DST = *(const bf16x8*)(smem + bb + (SI) * 4096 + row * 64 + \
          (kb ^ ((((unsigned)row >> 1) & 3) << 4))); }
#define LDB(SI, NI, DST) { \
    int row = wc * 32 + (NI) * 16 + l15; \
    DST = *(const bf16x8*)(smem + bb + 12288 + (SI) * 4096 + row * 64 + \
          (kb ^ ((((unsigned)row >> 1) & 3) << 4))); }
    LDA(0, 0, a0m0) LDA(0, 1, a0m1)
    LDA(1, 0, a1m0) LDA(1, 1, a1m1)
    LDA(2, 0, a2m0) LDA(2, 1, a2m1)
    LDB(0, 0, b0n0) LDB(0, 1, b0n1)
    LDB(1, 0, b1n0) LDB(1, 1, b1n1)
    LDB(2, 0, b2n0) LDB(2, 1, b2n1)
#undef LDA
#undef LDB
    PROD1(a0m0, a0m1, b2n0, b2n1)
    PROD1(a1m0, a1m1, b1n0, b1n1)
    PROD1(a2m0, a2m1, b0n0, b0n1)
    PROD1(a0m0, a0m1, b1n0, b1n1)
    PROD1(a1m0, a1m1, b0n0, b0n1)
    PROD1(a0m0, a0m1, b0n0, b0n1)
  };
  LOADS(0, aE0, aE1, bE0, bE1)
  LOADS(1, aO0, aO1, bO0, bO1)
  CONVW2(0, aE0, aE1, bE0, bE1)
  __syncthreads();
#pragma unroll 1
  for (int kk = 0; kk < 128; kk += 2) {
    if (kk + 2 < 128) { LOADS(kk + 2, aE0, aE1, bE0, bE1) }
    __builtin_amdgcn_sched_barrier(0);
    compute(0);
    CONVW2(24576, aO0, aO1, bO0, bO1)
    __syncthreads();
    if (kk + 3 < 128) { LOADS(kk + 3, aO0, aO1, bO0, bO1) }
    __builtin_amdgcn_sched_barrier(0);
    compute(24576);
    if (kk + 2 < 128) { CONVW2(0, aE0, aE1, bE0, bE1) }
    __syncthreads();
  }
  const int t0 = bm * 64;
  float* lf2 = (float*)smem;
#define EPI(MI, NI, ACC) \
  { _Pragma("unroll") \
    for (int r = 0; r < 4; ++r) { \
      int tl = wr * 32 + (MI) * 16 + lg * 4 + r; \
      int e  = wc * 32 + (NI) * 16 + l15; \
      float v = ACC[r]; \
      outl[(size_t)(t0 + tl) * NE + e] = v; \
      lf2[tl * 65 + e] = v; \
    } }
  EPI(0, 0, acc00) EPI(0, 1, acc01) EPI(1, 0, acc10) EPI(1, 1, acc11)
#undef EPI
  __syncthreads();
  if (tid < 64) {
    const int t = tid;
    float m1 = -1e30f, m2 = -1e30f;
    int i1 = 0, i2 = 0;
#pragma unroll
    for (int e = 0; e < NE; ++e) {
      float v = lf2[t * 65 + e];
      if (v > m1)      { m2 = m1; i2 = i1; m1 = v; i1 = e; }
      else if (v > m2) { m2 = v; i2 = e; }
    }
    float e2  = expf(m2 - m1);
    float inv = 1.0f / (1.0f + e2);
    outw[(size_t)(t0 + t) * 2 + 0] = inv;
    outw[(size_t)(t0 + t) * 2 + 1] = e2 * inv;
    outi[(size_t)(t0 + t) * 2 + 0] = (float)i1;
    outi[(size_t)(t0 + t) * 2 + 1] = (float)i2;
  }
}

extern "C" void kernel_launch(void* const* d_in, const int* in_sizes, int n_in,
                              void* d_out, int out_size, void* d_ws, size_t ws_size,
                              hipStream_t stream) {
  (void)in_sizes; (void)n_in; (void)out_size;
  const float* A = (const float*)d_in[0];   // hidden_states [32768][4096] f32
  const float* W = (const float*)d_in[1];   // gate_w [64][4096] f32
  float* outw = (float*)d_out;              // [T][2] weights
  float* outi = (float*)d_out + 2 * TT;     // [T][2] indices AS FLOATS
  float* outl = (float*)d_out + 4 * TT;     // [T][64] logits

  const size_t need = (size_t)128 * 3 * 4 * 1024;   // 1.5 MiB packed B
  if (ws_size >= need) {
    hipLaunchKernelGGL(prepack_w_kernel, dim3(128), dim3(256), 0, stream,
                       W, (uint4*)d_ws);
    hipLaunchKernelGGL(router_page_kernel, dim3(TT / MROWS), dim3(NT), 0, stream,
                       A, (const uint4*)d_ws, outw, outi, outl);
  } else {
    hipLaunchKernelGGL(topk_router_lds, dim3(TT / 64), dim3(256), 0, stream,
                       A, W, outw, outi, outl);
  }
}